// Round 3
// baseline (5037.140 us; speedup 1.0000x reference)
//
#include <hip/hip_runtime.h>

#define T_STEPS 64
#define BATCH   256
#define IN_SZ   1024
#define HID     4096
#define BLK     512
#define GATES   12288   // 3*HID
#define GROW    1536    // 3*BLK, rows per diagonal block

#define BM 128
#define BN 128
#define BK 64

// persistent step tile
#define BMT 64          // batch rows per workgroup
#define CN  64          // hidden cols per workgroup (64 | 1536 -> no block crossing)

using bf16x8  = __attribute__((ext_vector_type(8))) __bf16;
using floatx4 = __attribute__((ext_vector_type(4))) float;
typedef const __attribute__((address_space(1))) unsigned int* gas_u32;
typedef __attribute__((address_space(3))) unsigned int* las_u32;

__device__ __forceinline__ unsigned short f2bf(float f) {
    union { float f; unsigned int u; } v; v.f = f;
    unsigned int u = v.u;
    unsigned int r = (u + 0x7fffu + ((u >> 16) & 1u)) >> 16;
    return (unsigned short)r;
}

// ---- fp32 -> bf16 cast (vectorized x4) ----
__global__ __launch_bounds__(256) void cast_f32_bf16(
    const float* __restrict__ in, unsigned short* __restrict__ out, int n4)
{
    int i = blockIdx.x * 256 + threadIdx.x;
    if (i >= n4) return;
    float4 v = reinterpret_cast<const float4*>(in)[i];
    ushort4 o;
    o.x = f2bf(v.x); o.y = f2bf(v.y); o.z = f2bf(v.z); o.w = f2bf(v.w);
    reinterpret_cast<ushort4*>(out)[i] = o;
}

// ---- init h bf16 copy ----
__global__ __launch_bounds__(256) void init_h(
    const float* __restrict__ h0, unsigned short* __restrict__ hbf, int n)
{
    int i = blockIdx.x * 256 + threadIdx.x;
    if (i >= n) return;
    hbf[i] = f2bf(h0[i]);
}

// ---- zero the barrier counter (runs every launch / graph replay) ----
__global__ __launch_bounds__(64) void zero_u32(unsigned int* p, int n)
{
    int i = blockIdx.x * 64 + threadIdx.x;
    if (i < n) p[i] = 0u;
}

// ---- m97-style GEMM: C(M,GATES) = A(M,K) . B(GATES,K)^T (x-projection) ----
__global__ __launch_bounds__(256, 2) void gemm_abt(
    const unsigned short* __restrict__ Ag,
    const unsigned short* __restrict__ Bg,
    float* __restrict__ C,
    int lda, int K, int nt_count)
{
    __shared__ unsigned short lsA[BM * BK];
    __shared__ unsigned short lsB[BN * BK];

    const int bx = blockIdx.x;
    const int mt = bx / nt_count;
    const int nt = bx - mt * nt_count;
    const int m0 = mt * BM;
    const int n0 = nt * BN;

    const int tid  = threadIdx.x;
    const int wave = tid >> 6;
    const int lane = tid & 63;
    const int q    = lane >> 4;
    const int l16  = lane & 15;
    const int wm   = (wave >> 1) * 64;
    const int wn   = (wave & 1) * 64;

    floatx4 acc[4][4];
    #pragma unroll
    for (int mf = 0; mf < 4; mf++)
        #pragma unroll
        for (int nf = 0; nf < 4; nf++)
            acc[mf][nf] = floatx4{0.0f, 0.0f, 0.0f, 0.0f};

    for (int k0 = 0; k0 < K; k0 += BK) {
        __syncthreads();
        #pragma unroll
        for (int i = 0; i < 4; i++) {
            const int seg = wave * 4 + i;
            const int g   = seg * 64 + lane;
            const int row = g >> 3;
            const int cs  = ((g & 7) ^ (row & 7)) << 3;
            const unsigned short* ga = Ag + (size_t)(m0 + row) * lda + k0 + cs;
            __builtin_amdgcn_global_load_lds((gas_u32)ga,
                (las_u32)&lsA[seg * 512 + lane * 8], 16, 0, 0);
            const unsigned short* gb = Bg + (size_t)(n0 + row) * (size_t)K + k0 + cs;
            __builtin_amdgcn_global_load_lds((gas_u32)gb,
                (las_u32)&lsB[seg * 512 + lane * 8], 16, 0, 0);
        }
        __syncthreads();

        #pragma unroll
        for (int ks = 0; ks < BK; ks += 32) {
            bf16x8 a[4], b[4];
            #pragma unroll
            for (int mf = 0; mf < 4; mf++) {
                const int row = wm + mf * 16 + l16;
                const int pb  = ((ks >> 3) + q) ^ (row & 7);
                a[mf] = *reinterpret_cast<const bf16x8*>(&lsA[row * BK + pb * 8]);
            }
            #pragma unroll
            for (int nf = 0; nf < 4; nf++) {
                const int row = wn + nf * 16 + l16;
                const int pb  = ((ks >> 3) + q) ^ (row & 7);
                b[nf] = *reinterpret_cast<const bf16x8*>(&lsB[row * BK + pb * 8]);
            }
            #pragma unroll
            for (int mf = 0; mf < 4; mf++)
                #pragma unroll
                for (int nf = 0; nf < 4; nf++)
                    acc[mf][nf] = __builtin_amdgcn_mfma_f32_16x16x32_bf16(
                        a[mf], b[nf], acc[mf][nf], 0, 0, 0);
        }
    }

    #pragma unroll
    for (int mf = 0; mf < 4; mf++) {
        const int mrow0 = m0 + wm + mf * 16 + q * 4;
        #pragma unroll
        for (int nf = 0; nf < 4; nf++) {
            const int col = n0 + wn + nf * 16 + l16;
            #pragma unroll
            for (int r = 0; r < 4; r++)
                C[(size_t)(mrow0 + r) * GATES + col] = acc[mf][nf][r];
        }
    }
}

// ---- staging: one 64x256 A tile + one 64x256 B tile (32 KB each) ----
// LDS layout: row-pos p (0..31, 16B chunks) holds logical chunk p^(row&7).
// Per-thread constants: krow = tid>>5, kb = (tid&31)^(krow&7); row = it*8+krow.
__device__ __forceinline__ void stage_tile(
    const unsigned short* ap, const unsigned short* bp,
    unsigned short* la, unsigned short* lb, int tid)
{
    #pragma unroll
    for (int it = 0; it < 8; ++it) {
        __builtin_amdgcn_global_load_lds((gas_u32)(ap + it * 8 * HID),
            (las_u32)(la + (it * 256 + tid) * 8), 16, 0, 0);
        __builtin_amdgcn_global_load_lds((gas_u32)(bp + it * 8 * BLK),
            (las_u32)(lb + (it * 256 + tid) * 8), 16, 0, 0);
    }
}

// ---- compute: 64x64 output, K=256 chunk, 2x2 wave quadrants of 32x32 ----
__device__ __forceinline__ void gemm_chunk(
    const unsigned short* la, const unsigned short* lb,
    int wm, int wn, int q, int l16, floatx4 (&acc)[2][2])
{
    #pragma unroll
    for (int ks = 0; ks < 256; ks += 32) {
        bf16x8 a[2], b[2];
        #pragma unroll
        for (int mf = 0; mf < 2; mf++) {
            const int row = wm + mf * 16 + l16;
            const int pb  = ((ks >> 3) + q) ^ (row & 7);
            a[mf] = *reinterpret_cast<const bf16x8*>(&la[row * 256 + pb * 8]);
        }
        #pragma unroll
        for (int nf = 0; nf < 2; nf++) {
            const int row = wn + nf * 16 + l16;
            const int pb  = ((ks >> 3) + q) ^ (row & 7);
            b[nf] = *reinterpret_cast<const bf16x8*>(&lb[row * 256 + pb * 8]);
        }
        #pragma unroll
        for (int mf = 0; mf < 2; mf++)
            #pragma unroll
            for (int nf = 0; nf < 2; nf++)
                acc[mf][nf] = __builtin_amdgcn_mfma_f32_16x16x32_bf16(
                    a[mf], b[nf], acc[mf][nf], 0, 0, 0);
    }
}

// ---- hand-rolled grid barrier (device-scope atomics; no cooperative API) ----
// Release: per-thread fence + wg barrier, tid0 release-add. Wait: RELAXED spin
// (acquire-per-poll would buffer_inv every iteration and thrash co-XCD L2s).
// Depart: wg barrier + one acquire-side fence to invalidate stale L2 lines.
__device__ __forceinline__ void grid_barrier(unsigned int* cnt, unsigned int target)
{
    __threadfence();
    __syncthreads();
    if (threadIdx.x == 0) {
        __hip_atomic_fetch_add(cnt, 1u, __ATOMIC_RELEASE, __HIP_MEMORY_SCOPE_AGENT);
        while (__hip_atomic_load(cnt, __ATOMIC_RELAXED, __HIP_MEMORY_SCOPE_AGENT) < target)
            __builtin_amdgcn_s_sleep(2);
    }
    __syncthreads();
    __threadfence();
}

// ---- persistent GRU loop: all 64 steps in one kernel, plain launch ----
// 256 wgs (1/CU at 128 KB LDS -> exactly co-resident on 256 CUs).
// h state: bf16 ping-pong in ws (cross-wg), f32 in regs (own tile).
__global__ __launch_bounds__(256, 1) void persistent_gru(
    unsigned short* hbfA,                        // ping (t even: read A, write B)
    unsigned short* hbfB,
    const unsigned short* __restrict__ Whb,      // (12288,512) bf16
    const float* __restrict__ xg_all,            // (64,256,12288) f32
    const float* __restrict__ wib,               // (12288,)
    const float* __restrict__ bh,                // (12288,)
    const float* __restrict__ h0,                // (256,4096) f32
    float* __restrict__ hT,                      // (256,4096) final state
    float* __restrict__ out,                     // (64,256,4096)
    unsigned int* barrier_cnt)
{
    __shared__ unsigned short ls[2][2][64 * 256];   // [buf][A/B] 32 KB each = 128 KB

    const int bid  = blockIdx.x;
    const int g7   = bid & 7;           // XCD heuristic (round-robin dispatch)
    const int s    = bid >> 3;
    const int cidx = g7 * 8 + (s & 7);  // 8 hidden tiles per XCD
    const int bidx = s >> 3;
    const int b0   = bidx * BMT;
    const int c0   = cidx * CN;

    const int tid  = threadIdx.x;
    const int lane = tid & 63;
    const int wave = tid >> 6;
    const int q    = lane >> 4;
    const int l16  = lane & 15;
    const int wm   = (wave >> 1) * 32;
    const int wn   = (wave & 1) * 32;

    // staging per-thread constants
    const int krow = tid >> 5;                       // 0..7
    const int kb   = (tid & 31) ^ (krow & 7);        // fixed swizzled chunk

    // per-gate A column offsets (block-diagonal) and B row bases
    const int acol0 = ((0 * HID + c0) / GROW) * BLK;
    const int acol1 = ((1 * HID + c0) / GROW) * BLK;
    const int acol2 = ((2 * HID + c0) / GROW) * BLK;
    const unsigned short* bb0 = Whb + (size_t)(0 * HID + c0 + krow) * BLK + kb * 8;
    const unsigned short* bb1 = Whb + (size_t)(1 * HID + c0 + krow) * BLK + kb * 8;
    const unsigned short* bb2 = Whb + (size_t)(2 * HID + c0 + krow) * BLK + kb * 8;

    // biases (hoisted: depend only on column)
    float br[2], bz[2], bxn[2], bhn[2];
    #pragma unroll
    for (int nf = 0; nf < 2; nf++) {
        const int i = c0 + wn + nf * 16 + l16;
        br[nf]  = wib[i]           + bh[i];
        bz[nf]  = wib[HID + i]     + bh[HID + i];
        bxn[nf] = wib[2 * HID + i];
        bhn[nf] = bh[2 * HID + i];
    }

    // h state in registers (this wg's own 64x64 tile)
    float hreg[2][2][4];
    #pragma unroll
    for (int mf = 0; mf < 2; mf++)
        #pragma unroll
        for (int nf = 0; nf < 2; nf++)
            #pragma unroll
            for (int r = 0; r < 4; r++) {
                const int m = b0 + wm + mf * 16 + q * 4 + r;
                const int i = c0 + wn + nf * 16 + l16;
                hreg[mf][nf][r] = h0[(size_t)m * HID + i];
            }

    for (int t = 0; t < T_STEPS; t++) {
        const unsigned short* hin = (t & 1) ? hbfB : hbfA;
        unsigned short*      hout = (t & 1) ? hbfA : hbfB;
        const float* xgt = xg_all + (size_t)t * BATCH * GATES;
        float* outt = out + (size_t)t * BATCH * HID;

        const unsigned short* abase = hin + (size_t)(b0 + krow) * HID + kb * 8;

        floatx4 aR[2][2], aZ[2][2], aN[2][2];
        #pragma unroll
        for (int mf = 0; mf < 2; mf++)
            #pragma unroll
            for (int nf = 0; nf < 2; nf++) {
                aR[mf][nf] = floatx4{0.f, 0.f, 0.f, 0.f};
                aZ[mf][nf] = floatx4{0.f, 0.f, 0.f, 0.f};
                aN[mf][nf] = floatx4{0.f, 0.f, 0.f, 0.f};
            }

        // chunk 0 (gate0, half0) -> buf0; then xg prefetch (hides HBM latency
        // under the 6 staging chunks — drained by the chunk barriers anyway)
        stage_tile(abase + acol0, bb0, &ls[0][0][0], &ls[0][1][0], tid);

        float xpre[3][2][2][4];
        #pragma unroll
        for (int g = 0; g < 3; g++)
            #pragma unroll
            for (int mf = 0; mf < 2; mf++)
                #pragma unroll
                for (int r = 0; r < 4; r++) {
                    const size_t xb = (size_t)(b0 + wm + mf * 16 + q * 4 + r) * GATES + g * HID;
                    #pragma unroll
                    for (int nf = 0; nf < 2; nf++)
                        xpre[g][mf][nf][r] = xgt[xb + c0 + wn + nf * 16 + l16];
                }
        __syncthreads();                        // buf0 ready (vmcnt drain)

        // 2-phase pipeline over 6 chunks: (gate, half) =
        // (0,0)(0,1)(1,0)(1,1)(2,0)(2,1); stage next while computing current.
        stage_tile(abase + acol0 + 256, bb0 + 256, &ls[1][0][0], &ls[1][1][0], tid);
        gemm_chunk(&ls[0][0][0], &ls[0][1][0], wm, wn, q, l16, aR);
        __syncthreads();

        stage_tile(abase + acol1, bb1, &ls[0][0][0], &ls[0][1][0], tid);
        gemm_chunk(&ls[1][0][0], &ls[1][1][0], wm, wn, q, l16, aR);
        __syncthreads();

        stage_tile(abase + acol1 + 256, bb1 + 256, &ls[1][0][0], &ls[1][1][0], tid);
        gemm_chunk(&ls[0][0][0], &ls[0][1][0], wm, wn, q, l16, aZ);
        __syncthreads();

        stage_tile(abase + acol2, bb2, &ls[0][0][0], &ls[0][1][0], tid);
        gemm_chunk(&ls[1][0][0], &ls[1][1][0], wm, wn, q, l16, aZ);
        __syncthreads();

        stage_tile(abase + acol2 + 256, bb2 + 256, &ls[1][0][0], &ls[1][1][0], tid);
        gemm_chunk(&ls[0][0][0], &ls[0][1][0], wm, wn, q, l16, aN);
        __syncthreads();

        gemm_chunk(&ls[1][0][0], &ls[1][1][0], wm, wn, q, l16, aN);

        // pointwise epilogue (all in registers)
        #pragma unroll
        for (int mf = 0; mf < 2; mf++)
            #pragma unroll
            for (int nf = 0; nf < 2; nf++)
                #pragma unroll
                for (int r = 0; r < 4; r++) {
                    const float gr = xpre[0][mf][nf][r] + br[nf]  + aR[mf][nf][r];
                    const float gz = xpre[1][mf][nf][r] + bz[nf]  + aZ[mf][nf][r];
                    const float xn = xpre[2][mf][nf][r] + bxn[nf];
                    const float hn = aN[mf][nf][r] + bhn[nf];
                    const float rr = 1.0f / (1.0f + __expf(-gr));
                    const float zz = 1.0f / (1.0f + __expf(-gz));
                    const float nn = tanhf(xn + rr * hn);
                    const float hnew = (1.0f - zz) * nn + zz * hreg[mf][nf][r];
                    hreg[mf][nf][r] = hnew;
                    const int m = b0 + wm + mf * 16 + q * 4 + r;
                    const int i = c0 + wn + nf * 16 + l16;
                    const size_t hi = (size_t)m * HID + i;
                    outt[hi] = hnew;
                    hout[hi] = f2bf(hnew);
                }

        // full grid barrier: orders writes(t) -> reads(t+1) AND reads(t) ->
        // overwrites(t+1) (WAR on the ping-pong buffers).
        grid_barrier(barrier_cnt, (unsigned int)(t + 1) * 256u);
    }

    // final hidden state
    #pragma unroll
    for (int mf = 0; mf < 2; mf++)
        #pragma unroll
        for (int nf = 0; nf < 2; nf++)
            #pragma unroll
            for (int r = 0; r < 4; r++) {
                const int m = b0 + wm + mf * 16 + q * 4 + r;
                const int i = c0 + wn + nf * 16 + l16;
                hT[(size_t)m * HID + i] = hreg[mf][nf][r];
            }
}

extern "C" void kernel_launch(void* const* d_in, const int* in_sizes, int n_in,
                              void* d_out, int out_size, void* d_ws, size_t ws_size,
                              hipStream_t stream)
{
    const float* x   = (const float*)d_in[0];   // (64,256,1024)
    const float* h0  = (const float*)d_in[1];   // (256,4096)
    const float* Wi  = (const float*)d_in[2];   // (12288,1024)
    const float* Wib = (const float*)d_in[3];   // (12288,)
    const float* Wh  = (const float*)d_in[4];   // (8,1536,512)
    const float* bh  = (const float*)d_in[5];   // (12288,)

    float* out = (float*)d_out;                          // (64,256,4096)
    float* hT  = out + (size_t)T_STEPS * BATCH * HID;    // (256,4096)

    // workspace layout
    float* xg_all         = (float*)d_ws;                                  // 64*256*12288 f32 (805 MB)
    unsigned short* x_bf  = (unsigned short*)(xg_all + (size_t)T_STEPS * BATCH * GATES);
    unsigned short* wi_bf = x_bf  + (size_t)T_STEPS * BATCH * IN_SZ;       // 12288*1024
    unsigned short* wh_bf = wi_bf + (size_t)GATES * IN_SZ;                 // 12288*512
    unsigned short* hbf0  = wh_bf + (size_t)GATES * BLK;                   // 256*4096 ping
    unsigned short* hbf1  = hbf0  + (size_t)BATCH * HID;                   // 256*4096 pong
    unsigned int* bar_cnt = (unsigned int*)(hbf1 + (size_t)BATCH * HID);   // barrier counter

    const int n_x  = T_STEPS * BATCH * IN_SZ;   // 16,777,216
    const int n_wi = GATES * IN_SZ;             // 12,582,912
    const int n_wh = GATES * BLK;               //  6,291,456

    cast_f32_bf16<<<(n_x / 4 + 255) / 256, 256, 0, stream>>>(x,  x_bf,  n_x / 4);
    cast_f32_bf16<<<(n_wi / 4 + 255) / 256, 256, 0, stream>>>(Wi, wi_bf, n_wi / 4);
    cast_f32_bf16<<<(n_wh / 4 + 255) / 256, 256, 0, stream>>>(Wh, wh_bf, n_wh / 4);
    init_h<<<(BATCH * HID + 255) / 256, 256, 0, stream>>>(h0, hbf0, BATCH * HID);
    zero_u32<<<1, 64, 0, stream>>>(bar_cnt, 1);   // re-arm barrier each launch/replay

    // Hoisted x-projection: (16384 x 1024) . (12288 x 1024)^T -> (16384 x 12288)
    gemm_abt<<<(T_STEPS * BATCH / BM) * (GATES / BN), 256, 0, stream>>>(
        x_bf, wi_bf, xg_all, IN_SZ, IN_SZ, GATES / BN);

    // persistent loop: 256 wgs = 1 per CU (128 KB LDS), plain launch
    persistent_gru<<<dim3(256), dim3(256), 0, stream>>>(
        hbf0, hbf1, wh_bf, xg_all, Wib, bh, h0, hT, out, bar_cnt);
}

// Round 4
// 1757.330 us; speedup vs baseline: 2.8664x; 2.8664x over previous
//
#include <hip/hip_runtime.h>

#define T_STEPS 64
#define BATCH   256
#define IN_SZ   1024
#define HID     4096
#define BLK     512
#define GATES   12288   // 3*HID
#define GROW    1536    // 3*BLK, rows per diagonal block

#define BM 128
#define BN 128
#define BK 64

// persistent step tile
#define BMT 64          // batch rows per workgroup
#define CN  64          // hidden cols per workgroup (64 | 1536 -> no block crossing)

// CPol bits (LLVM SIDefines): SC0=GLC=1, NT=SLC=2, SC1=SCC=16
#define CPOL_SC0_SC1 17

using bf16x8  = __attribute__((ext_vector_type(8))) __bf16;
using floatx4 = __attribute__((ext_vector_type(4))) float;
typedef const __attribute__((address_space(1))) unsigned int* gas_u32;
typedef __attribute__((address_space(3))) unsigned int* las_u32;

__device__ __forceinline__ unsigned short f2bf(float f) {
    union { float f; unsigned int u; } v; v.f = f;
    unsigned int u = v.u;
    unsigned int r = (u + 0x7fffu + ((u >> 16) & 1u)) >> 16;
    return (unsigned short)r;
}

// ---- fp32 -> bf16 cast (vectorized x4) ----
__global__ __launch_bounds__(256) void cast_f32_bf16(
    const float* __restrict__ in, unsigned short* __restrict__ out, int n4)
{
    int i = blockIdx.x * 256 + threadIdx.x;
    if (i >= n4) return;
    float4 v = reinterpret_cast<const float4*>(in)[i];
    ushort4 o;
    o.x = f2bf(v.x); o.y = f2bf(v.y); o.z = f2bf(v.z); o.w = f2bf(v.w);
    reinterpret_cast<ushort4*>(out)[i] = o;
}

// ---- init h bf16 copy ----
__global__ __launch_bounds__(256) void init_h(
    const float* __restrict__ h0, unsigned short* __restrict__ hbf, int n)
{
    int i = blockIdx.x * 256 + threadIdx.x;
    if (i >= n) return;
    hbf[i] = f2bf(h0[i]);
}

// ---- zero barrier counters (runs every launch / graph replay) ----
__global__ __launch_bounds__(64) void zero_u32(unsigned int* p, int n)
{
    int i = blockIdx.x * 64 + threadIdx.x;
    if (i < n) p[i] = 0u;
}

// ---- m97-style GEMM: C(M,GATES) = A(M,K) . B(GATES,K)^T (x-projection) ----
__global__ __launch_bounds__(256, 2) void gemm_abt(
    const unsigned short* __restrict__ Ag,
    const unsigned short* __restrict__ Bg,
    float* __restrict__ C,
    int lda, int K, int nt_count)
{
    __shared__ unsigned short lsA[BM * BK];
    __shared__ unsigned short lsB[BN * BK];

    const int bx = blockIdx.x;
    const int mt = bx / nt_count;
    const int nt = bx - mt * nt_count;
    const int m0 = mt * BM;
    const int n0 = nt * BN;

    const int tid  = threadIdx.x;
    const int wave = tid >> 6;
    const int lane = tid & 63;
    const int q    = lane >> 4;
    const int l16  = lane & 15;
    const int wm   = (wave >> 1) * 64;
    const int wn   = (wave & 1) * 64;

    floatx4 acc[4][4];
    #pragma unroll
    for (int mf = 0; mf < 4; mf++)
        #pragma unroll
        for (int nf = 0; nf < 4; nf++)
            acc[mf][nf] = floatx4{0.0f, 0.0f, 0.0f, 0.0f};

    for (int k0 = 0; k0 < K; k0 += BK) {
        __syncthreads();
        #pragma unroll
        for (int i = 0; i < 4; i++) {
            const int seg = wave * 4 + i;
            const int g   = seg * 64 + lane;
            const int row = g >> 3;
            const int cs  = ((g & 7) ^ (row & 7)) << 3;
            const unsigned short* ga = Ag + (size_t)(m0 + row) * lda + k0 + cs;
            __builtin_amdgcn_global_load_lds((gas_u32)ga,
                (las_u32)&lsA[seg * 512 + lane * 8], 16, 0, 0);
            const unsigned short* gb = Bg + (size_t)(n0 + row) * (size_t)K + k0 + cs;
            __builtin_amdgcn_global_load_lds((gas_u32)gb,
                (las_u32)&lsB[seg * 512 + lane * 8], 16, 0, 0);
        }
        __syncthreads();

        #pragma unroll
        for (int ks = 0; ks < BK; ks += 32) {
            bf16x8 a[4], b[4];
            #pragma unroll
            for (int mf = 0; mf < 4; mf++) {
                const int row = wm + mf * 16 + l16;
                const int pb  = ((ks >> 3) + q) ^ (row & 7);
                a[mf] = *reinterpret_cast<const bf16x8*>(&lsA[row * BK + pb * 8]);
            }
            #pragma unroll
            for (int nf = 0; nf < 4; nf++) {
                const int row = wn + nf * 16 + l16;
                const int pb  = ((ks >> 3) + q) ^ (row & 7);
                b[nf] = *reinterpret_cast<const bf16x8*>(&lsB[row * BK + pb * 8]);
            }
            #pragma unroll
            for (int mf = 0; mf < 4; mf++)
                #pragma unroll
                for (int nf = 0; nf < 4; nf++)
                    acc[mf][nf] = __builtin_amdgcn_mfma_f32_16x16x32_bf16(
                        a[mf], b[nf], acc[mf][nf], 0, 0, 0);
        }
    }

    #pragma unroll
    for (int mf = 0; mf < 4; mf++) {
        const int mrow0 = m0 + wm + mf * 16 + q * 4;
        #pragma unroll
        for (int nf = 0; nf < 4; nf++) {
            const int col = n0 + wn + nf * 16 + l16;
            #pragma unroll
            for (int r = 0; r < 4; r++)
                C[(size_t)(mrow0 + r) * GATES + col] = acc[mf][nf][r];
        }
    }
}

// ---- staging: one 64x256 A tile (h, coherent sc0|sc1) + one 64x256 B tile ----
// LDS layout: row-pos p (0..31, 16B chunks) holds logical chunk p^(row&7).
__device__ __forceinline__ void stage_tile(
    const unsigned short* ap, const unsigned short* bp,
    unsigned short* la, unsigned short* lb, int tid)
{
    #pragma unroll
    for (int it = 0; it < 8; ++it) {
        // A = h ping-pong: load at coherence point (bypass possibly-stale L2)
        __builtin_amdgcn_global_load_lds((gas_u32)(ap + it * 8 * HID),
            (las_u32)(la + (it * 256 + tid) * 8), 16, 0, CPOL_SC0_SC1);
        // B = weights: normal cached path (stays L2-resident across steps)
        __builtin_amdgcn_global_load_lds((gas_u32)(bp + it * 8 * BLK),
            (las_u32)(lb + (it * 256 + tid) * 8), 16, 0, 0);
    }
}

// ---- compute: 64x64 output, K=256 chunk, 2x2 wave quadrants of 32x32 ----
__device__ __forceinline__ void gemm_chunk(
    const unsigned short* la, const unsigned short* lb,
    int wm, int wn, int q, int l16, floatx4 (&acc)[2][2])
{
    #pragma unroll
    for (int ks = 0; ks < 256; ks += 32) {
        bf16x8 a[2], b[2];
        #pragma unroll
        for (int mf = 0; mf < 2; mf++) {
            const int row = wm + mf * 16 + l16;
            const int pb  = ((ks >> 3) + q) ^ (row & 7);
            a[mf] = *reinterpret_cast<const bf16x8*>(&la[row * 256 + pb * 8]);
        }
        #pragma unroll
        for (int nf = 0; nf < 2; nf++) {
            const int row = wn + nf * 16 + l16;
            const int pb  = ((ks >> 3) + q) ^ (row & 7);
            b[nf] = *reinterpret_cast<const bf16x8*>(&lb[row * 256 + pb * 8]);
        }
        #pragma unroll
        for (int mf = 0; mf < 2; mf++)
            #pragma unroll
            for (int nf = 0; nf < 2; nf++)
                acc[mf][nf] = __builtin_amdgcn_mfma_f32_16x16x32_bf16(
                    a[mf], b[nf], acc[mf][nf], 0, 0, 0);
    }
}

// ---- per-group barrier: relaxed atomics, NO agent fences (no L2 inv/wb). ----
// h data coherence is carried by the sc0|sc1 path; each wave drains its own
// vmem stores (s_waitcnt vmcnt(0)) BEFORE __syncthreads, so arrival implies
// the group's h stores are at the coherence point.
__device__ __forceinline__ void group_barrier(unsigned int* cnt, unsigned int target)
{
    __syncthreads();
    if (threadIdx.x == 0) {
        __hip_atomic_fetch_add(cnt, 1u, __ATOMIC_RELAXED, __HIP_MEMORY_SCOPE_AGENT);
        unsigned int v;
        do {
            __builtin_amdgcn_s_sleep(1);
            asm volatile("global_load_dword %0, %1, off sc0 sc1\n\ts_waitcnt vmcnt(0)"
                         : "=v"(v) : "v"(cnt) : "memory");
        } while (v < target);
    }
    __syncthreads();
}

// ---- persistent GRU loop: all 64 steps in one kernel, plain launch ----
// 256 wgs (1/CU at 128 KB LDS -> exactly co-resident). Sync is per-bidx-group
// (64 wgs): h-GEMM of wg (bidx,cidx) only reads h rows produced by its own
// bidx group, so groups never need to sync with each other.
__global__ __launch_bounds__(256, 1) void persistent_gru(
    unsigned short* hbfA,                        // ping (t even: read A, write B)
    unsigned short* hbfB,
    const unsigned short* __restrict__ Whb,      // (12288,512) bf16
    const float* __restrict__ xg_all,            // (64,256,12288) f32
    const float* __restrict__ wib,               // (12288,)
    const float* __restrict__ bh,                // (12288,)
    const float* __restrict__ h0,                // (256,4096) f32
    float* __restrict__ hT,                      // (256,4096) final state
    float* __restrict__ out,                     // (64,256,4096)
    unsigned int* bar)                           // 4 counters, 128B apart
{
    __shared__ unsigned short ls[2][2][64 * 256];   // [buf][A/B] 32 KB each = 128 KB

    const int bid  = blockIdx.x;
    const int g7   = bid & 7;           // XCD heuristic (round-robin dispatch)
    const int s    = bid >> 3;
    const int cidx = g7 * 8 + (s & 7);  // 8 hidden tiles per XCD
    const int bidx = s >> 3;            // == bid >> 6: group = 64 consecutive bids
    const int b0   = bidx * BMT;
    const int c0   = cidx * CN;
    unsigned int* gcnt = bar + (bid >> 6) * 32;   // per-group counter, own line

    const int tid  = threadIdx.x;
    const int lane = tid & 63;
    const int wave = tid >> 6;
    const int q    = lane >> 4;
    const int l16  = lane & 15;
    const int wm   = (wave >> 1) * 32;
    const int wn   = (wave & 1) * 32;

    // staging per-thread constants
    const int krow = tid >> 5;                       // 0..7
    const int kb   = (tid & 31) ^ (krow & 7);        // fixed swizzled chunk

    // per-gate A column offsets (block-diagonal) and B row bases
    const int acol0 = ((0 * HID + c0) / GROW) * BLK;
    const int acol1 = ((1 * HID + c0) / GROW) * BLK;
    const int acol2 = ((2 * HID + c0) / GROW) * BLK;
    const unsigned short* bb0 = Whb + (size_t)(0 * HID + c0 + krow) * BLK + kb * 8;
    const unsigned short* bb1 = Whb + (size_t)(1 * HID + c0 + krow) * BLK + kb * 8;
    const unsigned short* bb2 = Whb + (size_t)(2 * HID + c0 + krow) * BLK + kb * 8;

    // biases (hoisted: depend only on column)
    float br[2], bz[2], bxn[2], bhn[2];
    #pragma unroll
    for (int nf = 0; nf < 2; nf++) {
        const int i = c0 + wn + nf * 16 + l16;
        br[nf]  = wib[i]           + bh[i];
        bz[nf]  = wib[HID + i]     + bh[HID + i];
        bxn[nf] = wib[2 * HID + i];
        bhn[nf] = bh[2 * HID + i];
    }

    // h state in registers (this wg's own 64x64 tile)
    float hreg[2][2][4];
    #pragma unroll
    for (int mf = 0; mf < 2; mf++)
        #pragma unroll
        for (int nf = 0; nf < 2; nf++)
            #pragma unroll
            for (int r = 0; r < 4; r++) {
                const int m = b0 + wm + mf * 16 + q * 4 + r;
                const int i = c0 + wn + nf * 16 + l16;
                hreg[mf][nf][r] = h0[(size_t)m * HID + i];
            }

    for (int t = 0; t < T_STEPS; t++) {
        const unsigned short* hin = (t & 1) ? hbfB : hbfA;
        unsigned short*      hout = (t & 1) ? hbfA : hbfB;
        const float* xgt = xg_all + (size_t)t * BATCH * GATES;
        float* outt = out + (size_t)t * BATCH * HID;

        const unsigned short* abase = hin + (size_t)(b0 + krow) * HID + kb * 8;

        floatx4 aR[2][2], aZ[2][2], aN[2][2];
        #pragma unroll
        for (int mf = 0; mf < 2; mf++)
            #pragma unroll
            for (int nf = 0; nf < 2; nf++) {
                aR[mf][nf] = floatx4{0.f, 0.f, 0.f, 0.f};
                aZ[mf][nf] = floatx4{0.f, 0.f, 0.f, 0.f};
                aN[mf][nf] = floatx4{0.f, 0.f, 0.f, 0.f};
            }

        // chunk 0 (gate0, half0) -> buf0; then xg prefetch (hides HBM latency
        // under the 6 staging chunks — drained by the chunk barriers anyway)
        stage_tile(abase + acol0, bb0, &ls[0][0][0], &ls[0][1][0], tid);

        float xpre[3][2][2][4];
        #pragma unroll
        for (int g = 0; g < 3; g++)
            #pragma unroll
            for (int mf = 0; mf < 2; mf++)
                #pragma unroll
                for (int r = 0; r < 4; r++) {
                    const size_t xb = (size_t)(b0 + wm + mf * 16 + q * 4 + r) * GATES + g * HID;
                    #pragma unroll
                    for (int nf = 0; nf < 2; nf++)
                        xpre[g][mf][nf][r] = xgt[xb + c0 + wn + nf * 16 + l16];
                }
        __syncthreads();                        // buf0 ready (vmcnt drain)

        // 2-phase pipeline over 6 chunks: (gate, half) =
        // (0,0)(0,1)(1,0)(1,1)(2,0)(2,1); stage next while computing current.
        stage_tile(abase + acol0 + 256, bb0 + 256, &ls[1][0][0], &ls[1][1][0], tid);
        gemm_chunk(&ls[0][0][0], &ls[0][1][0], wm, wn, q, l16, aR);
        __syncthreads();

        stage_tile(abase + acol1, bb1, &ls[0][0][0], &ls[0][1][0], tid);
        gemm_chunk(&ls[1][0][0], &ls[1][1][0], wm, wn, q, l16, aR);
        __syncthreads();

        stage_tile(abase + acol1 + 256, bb1 + 256, &ls[1][0][0], &ls[1][1][0], tid);
        gemm_chunk(&ls[0][0][0], &ls[0][1][0], wm, wn, q, l16, aZ);
        __syncthreads();

        stage_tile(abase + acol2, bb2, &ls[0][0][0], &ls[0][1][0], tid);
        gemm_chunk(&ls[1][0][0], &ls[1][1][0], wm, wn, q, l16, aZ);
        __syncthreads();

        stage_tile(abase + acol2 + 256, bb2 + 256, &ls[1][0][0], &ls[1][1][0], tid);
        gemm_chunk(&ls[0][0][0], &ls[0][1][0], wm, wn, q, l16, aN);
        __syncthreads();

        gemm_chunk(&ls[1][0][0], &ls[1][1][0], wm, wn, q, l16, aN);

        // pointwise epilogue (all in registers); h goes out via sc0|sc1 stores
        #pragma unroll
        for (int mf = 0; mf < 2; mf++)
            #pragma unroll
            for (int nf = 0; nf < 2; nf++)
                #pragma unroll
                for (int r = 0; r < 4; r++) {
                    const float gr = xpre[0][mf][nf][r] + br[nf]  + aR[mf][nf][r];
                    const float gz = xpre[1][mf][nf][r] + bz[nf]  + aZ[mf][nf][r];
                    const float xn = xpre[2][mf][nf][r] + bxn[nf];
                    const float hn = aN[mf][nf][r] + bhn[nf];
                    const float rr = 1.0f / (1.0f + __expf(-gr));
                    const float zz = 1.0f / (1.0f + __expf(-gz));
                    const float nn = tanhf(xn + rr * hn);
                    const float hnew = (1.0f - zz) * nn + zz * hreg[mf][nf][r];
                    hreg[mf][nf][r] = hnew;
                    const int m = b0 + wm + mf * 16 + q * 4 + r;
                    const int i = c0 + wn + nf * 16 + l16;
                    const size_t hi = (size_t)m * HID + i;
                    outt[hi] = hnew;
                    asm volatile("global_store_short %0, %1, off sc0 sc1"
                                 :: "v"(hout + hi), "v"((unsigned int)f2bf(hnew))
                                 : "memory");
                }

        // drain this wave's h stores to the coherence point, then group barrier
        asm volatile("s_waitcnt vmcnt(0)" ::: "memory");
        group_barrier(gcnt, 64u * (unsigned int)(t + 1));
    }

    // final hidden state
    #pragma unroll
    for (int mf = 0; mf < 2; mf++)
        #pragma unroll
        for (int nf = 0; nf < 2; nf++)
            #pragma unroll
            for (int r = 0; r < 4; r++) {
                const int m = b0 + wm + mf * 16 + q * 4 + r;
                const int i = c0 + wn + nf * 16 + l16;
                hT[(size_t)m * HID + i] = hreg[mf][nf][r];
            }
}

extern "C" void kernel_launch(void* const* d_in, const int* in_sizes, int n_in,
                              void* d_out, int out_size, void* d_ws, size_t ws_size,
                              hipStream_t stream)
{
    const float* x   = (const float*)d_in[0];   // (64,256,1024)
    const float* h0  = (const float*)d_in[1];   // (256,4096)
    const float* Wi  = (const float*)d_in[2];   // (12288,1024)
    const float* Wib = (const float*)d_in[3];   // (12288,)
    const float* Wh  = (const float*)d_in[4];   // (8,1536,512)
    const float* bh  = (const float*)d_in[5];   // (12288,)

    float* out = (float*)d_out;                          // (64,256,4096)
    float* hT  = out + (size_t)T_STEPS * BATCH * HID;    // (256,4096)

    // workspace layout
    float* xg_all         = (float*)d_ws;                                  // 64*256*12288 f32 (805 MB)
    unsigned short* x_bf  = (unsigned short*)(xg_all + (size_t)T_STEPS * BATCH * GATES);
    unsigned short* wi_bf = x_bf  + (size_t)T_STEPS * BATCH * IN_SZ;       // 12288*1024
    unsigned short* wh_bf = wi_bf + (size_t)GATES * IN_SZ;                 // 12288*512
    unsigned short* hbf0  = wh_bf + (size_t)GATES * BLK;                   // 256*4096 ping
    unsigned short* hbf1  = hbf0  + (size_t)BATCH * HID;                   // 256*4096 pong
    unsigned int* bar_cnt = (unsigned int*)(hbf1 + (size_t)BATCH * HID);   // 4 counters, 128B apart

    const int n_x  = T_STEPS * BATCH * IN_SZ;   // 16,777,216
    const int n_wi = GATES * IN_SZ;             // 12,582,912
    const int n_wh = GATES * BLK;               //  6,291,456

    cast_f32_bf16<<<(n_x / 4 + 255) / 256, 256, 0, stream>>>(x,  x_bf,  n_x / 4);
    cast_f32_bf16<<<(n_wi / 4 + 255) / 256, 256, 0, stream>>>(Wi, wi_bf, n_wi / 4);
    cast_f32_bf16<<<(n_wh / 4 + 255) / 256, 256, 0, stream>>>(Wh, wh_bf, n_wh / 4);
    init_h<<<(BATCH * HID + 255) / 256, 256, 0, stream>>>(h0, hbf0, BATCH * HID);
    zero_u32<<<2, 64, 0, stream>>>(bar_cnt, 128);   // re-arm barriers each launch/replay

    // Hoisted x-projection: (16384 x 1024) . (12288 x 1024)^T -> (16384 x 12288)
    gemm_abt<<<(T_STEPS * BATCH / BM) * (GATES / BN), 256, 0, stream>>>(
        x_bf, wi_bf, xg_all, IN_SZ, IN_SZ, GATES / BN);

    // persistent loop: 256 wgs = 1 per CU (128 KB LDS), plain launch
    persistent_gru<<<dim3(256), dim3(256), 0, stream>>>(
        hbf0, hbf1, wh_bf, xg_all, Wib, bh, h0, hT, out, bar_cnt);
}